// Round 9
// baseline (244.314 us; speedup 1.0000x reference)
//
#include <hip/hip_runtime.h>
#include <stdint.h>

#define N_PTS 8192
#define SEG 1024

typedef __attribute__((ext_vector_type(4))) float f32x4;

// d^2 exactly as numpy/jax f32: mul,mul,mul,(add),add — no FMA contraction.
__device__ __forceinline__ float sq3(float dx, float dy, float dz) {
#pragma clang fp contract(off)
    float xx = dx * dx;
    float yy = dy * dy;
    float zz = dz * dz;
    return (xx + yy) + zz;
}

// Cross-lane broadcast through the register file.
__device__ __forceinline__ float bcastf(float v, int k) {
    return __int_as_float(__builtin_amdgcn_readlane(__float_as_int(v), k));
}

__global__ __launch_bounds__(256)
void sa_lds(const float* __restrict__ pos,
            const float* __restrict__ W1, const float* __restrict__ b1,
            const float* __restrict__ g1, const float* __restrict__ be1,
            const float* __restrict__ m1, const float* __restrict__ v1,
            const float* __restrict__ W2, const float* __restrict__ b2,
            const float* __restrict__ g2, const float* __restrict__ be2,
            const float* __restrict__ m2, const float* __restrict__ v2,
            const float* __restrict__ W3, const float* __restrict__ b3,
            const float* __restrict__ g3, const float* __restrict__ be3,
            const float* __restrict__ m3, const float* __restrict__ v3,
            float* __restrict__ out, int* __restrict__ ctr)
{
    __shared__ float a1s[64], c1s[64], a2s[64], c2s[64];
    // Swizzled weight tiles, shared by all 4 waves.
    // w2lds: (c,k) at c*64 + (((k>>2)^(c&7))<<2) + (k&3)            [16 KB]
    // w3lds: (c,k,ab) at c*128 + ((((k>>1)^(c&7))<<2) | ((k&1)<<1) | ab) [32 KB]
    __shared__ __align__(16) float w2lds[64 * 64];
    __shared__ __align__(16) float w3lds[64 * 128];
    __shared__ int nbrs[4][64];

    const int tid  = threadIdx.x;
    const int lane = tid & 63;
    const int w    = tid >> 6;
    const int c    = lane;

    // ---------- BN affine coefficients ----------
    if (tid < 64) {
        float a1 = g1[tid] / sqrtf(v1[tid] + 1e-5f);
        a1s[tid] = a1;
        c1s[tid] = be1[tid] - m1[tid] * a1;
        float a2 = g2[tid] / sqrtf(v2[tid] + 1e-5f);
        a2s[tid] = a2;
        c2s[tid] = be2[tid] - m2[tid] * a2;
    }
    __syncthreads();

    // ---------- stage folded weights into swizzled LDS (once per block) ----------
    for (int idx = tid; idx < 4096; idx += 256) {           // W2' = diag(a1) @ W2
        int cc = idx & 63, k = idx >> 6;
        float val = a1s[k] * W2[k * 64 + cc];
        int phys = cc * 64 + ((((k >> 2) ^ (cc & 7)) << 2) | (k & 3));
        w2lds[phys] = val;
    }
    for (int idx = tid; idx < 8192; idx += 256) {           // W3' = diag(a2) @ W3
        int cc = idx & 63, f = idx >> 6;
        int k = f >> 1, ab = f & 1;
        float val = a2s[k] * W3[k * 128 + ab * 64 + cc];
        int phys = cc * 128 + ((((k >> 1) ^ (cc & 7)) << 2) | ((k & 1) << 1) | ab);
        w3lds[phys] = val;
    }

    // ---------- per-lane constants (lane = channel c) ----------
    const float w1x = W1[c], w1y = W1[64 + c], w1z = W1[128 + c];
    const float b1v = b1[c];

    float b2c = b2[c];
#pragma unroll 8
    for (int k = 0; k < 64; ++k) b2c = fmaf(c1s[k], W2[k * 64 + c], b2c);

    float b3a = b3[c], b3b = b3[64 + c];
#pragma unroll 8
    for (int k = 0; k < 64; ++k) {
        b3a = fmaf(c2s[k], W3[k * 128 + c], b3a);
        b3b = fmaf(c2s[k], W3[k * 128 + 64 + c], b3b);
    }

    const float a3a = g3[c] / sqrtf(v3[c] + 1e-5f);
    const float c3a = be3[c] - m3[c] * a3a;
    const float a3b = g3[64 + c] / sqrtf(v3[64 + c] + 1e-5f);
    const float c3b = be3[64 + c] - m3[64 + c] * a3b;

    __syncthreads();   // weights staged; everything below is wave-local

    // Per-lane swizzled base byte-offsets (XOR field disjoint from row bits).
    const int sbase2 = c * 256 + ((c & 7) << 4);
    const int sbase3 = c * 512 + ((c & 7) << 4);
    const char* w2p = (const char*)w2lds;
    const char* w3p = (const char*)w3lds;

    const float R2 = (float)(0.2 * 0.2);   // f32(0.04), one ulp below 0.2f*0.2f
    const unsigned R2bits = __float_as_uint(R2);
    const unsigned long long below = (1ULL << lane) - 1ULL;

    // ---------- dynamic per-point work queue ----------
    for (;;) {
        int p0 = 0;
        if (lane == 0) p0 = atomicAdd(ctr, 1);
        const int p = __builtin_amdgcn_readfirstlane(p0);
        if (p >= N_PTS) break;

        const int base = p & ~(SEG - 1);
        const float px = pos[p * 3 + 0], py = pos[p * 3 + 1], pz = pos[p * 3 + 2];

        // ---- ball query: 1024 candidates, 16 per lane (proven exact) ----
        unsigned bits[16];
        int cnt = 0;
#pragma unroll
        for (int s = 0; s < 16; ++s) {
            int j = base + s * 64 + lane;
            float dx = pos[j * 3 + 0] - px;
            float dy = pos[j * 3 + 1] - py;
            float dz = pos[j * 3 + 2] - pz;
            float d2 = sq3(dx, dy, dz);
            bool ok = (d2 <= R2);
            bits[s] = ok ? __float_as_uint(d2) : 0xFFFFFFFFu;
            cnt += __popcll(__ballot(ok));
        }

        unsigned selm = 0;
        if (cnt <= 64) {
#pragma unroll
            for (int s = 0; s < 16; ++s)
                selm |= (bits[s] != 0xFFFFFFFFu ? 1u : 0u) << s;
        } else {
            // exact 64-smallest selection, index tie-break (matches lax.top_k)
            unsigned lo = 0, hi = R2bits;
            while (lo < hi) {
                unsigned mid = lo + ((hi - lo) >> 1);
                int cc = 0;
#pragma unroll
                for (int s = 0; s < 16; ++s)
                    cc += __popcll(__ballot(bits[s] <= mid));
                if (cc >= 64) hi = mid; else lo = mid + 1;
            }
            const unsigned T = lo;
            int c1n = 0;
#pragma unroll
            for (int s = 0; s < 16; ++s)
                c1n += __popcll(__ballot(bits[s] < T));
            const int need = 64 - c1n;
            int eqbase = 0;
#pragma unroll
            for (int s = 0; s < 16; ++s) {
                unsigned long long em = __ballot(bits[s] == T);
                int rank = eqbase + __popcll(em & below);
                bool sel = (bits[s] < T) | ((bits[s] == T) & (rank < need));
                selm |= (sel ? 1u : 0u) << s;
                eqbase += __popcll(em);
            }
        }

        // ---- compact selected neighbor indices into LDS ----
        int nsel = 0;
#pragma unroll
        for (int s = 0; s < 16; ++s) {
            bool sel = (selm >> s) & 1u;
            unsigned long long m = __ballot(sel);
            int mypos = nsel + __popcll(m & below);
            if (sel) nbrs[w][mypos] = base + s * 64 + lane;
            nsel += __popcll(m);
        }
        asm volatile("s_waitcnt lgkmcnt(0)" ::: "memory");

        // lane e holds edge e's relative position
        const int myj = (lane < nsel) ? nbrs[w][lane] : p;
        const float relx = pos[myj * 3 + 0] - px;
        const float rely = pos[myj * 3 + 1] - py;
        const float relz = pos[myj * 3 + 2] - pz;

        // ---- MLP + max: 8-edge batches, k-outer, weights from swizzled LDS ----
        float mx0 = 0.f, mx1 = 0.f;
        const int nb = (nsel + 7) >> 3;
        for (int bb = 0; bb < nb; ++bb) {
            const int eb = bb * 8;

            // L1: lane's channel for 8 edges (dup-pad tail with last edge; max-safe)
            float h1v[8];
#pragma unroll
            for (int j = 0; j < 8; ++j) {
                int ej = eb + j;  ej = (ej < nsel) ? ej : (nsel - 1);
                float rx = bcastf(relx, ej);
                float ry = bcastf(rely, ej);
                float rz = bcastf(relz, ej);
                h1v[j] = fmaxf(fmaf(rx, w1x, fmaf(ry, w1y, fmaf(rz, w1z, b1v))), 0.f);
            }

            // L2: z2[c][j] = b2c + sum_k h1[k][j] * W2'[k][c]
            float z2v[8];
#pragma unroll
            for (int j = 0; j < 8; ++j) z2v[j] = b2c;
            f32x4 wv = *(const f32x4*)(w2p + (sbase2 ^ 0));
            for (int g = 0; g < 16; ++g) {
                f32x4 wn = *(const f32x4*)(w2p + (sbase2 ^ (((g + 1) & 15) << 4)));
#pragma unroll
                for (int kk = 0; kk < 4; ++kk) {
                    const int k = g * 4 + kk;   // wave-uniform -> SGPR readlane
#pragma unroll
                    for (int j = 0; j < 8; ++j)
                        z2v[j] = fmaf(bcastf(h1v[j], k), wv[kk], z2v[j]);
                }
                wv = wn;
            }
            float h2v[8];
#pragma unroll
            for (int j = 0; j < 8; ++j) h2v[j] = fmaxf(z2v[j], 0.f);

            // L3: r[j] = sum_k h2[k][j]*w3a[k][c], s[j] likewise for w3b
            float rv[8], sv[8];
#pragma unroll
            for (int j = 0; j < 8; ++j) { rv[j] = 0.f; sv[j] = 0.f; }
            f32x4 w3v = *(const f32x4*)(w3p + (sbase3 ^ 0));
            for (int p2 = 0; p2 < 32; ++p2) {
                f32x4 w3n = *(const f32x4*)(w3p + (sbase3 ^ (((p2 + 1) & 31) << 4)));
                const int k0 = p2 * 2;
#pragma unroll
                for (int j = 0; j < 8; ++j) {
                    float u0 = bcastf(h2v[j], k0);
                    float u1 = bcastf(h2v[j], k0 + 1);
                    rv[j] = fmaf(u0, w3v[0], rv[j]);  sv[j] = fmaf(u0, w3v[1], sv[j]);
                    rv[j] = fmaf(u1, w3v[2], rv[j]);  sv[j] = fmaf(u1, w3v[3], sv[j]);
                }
                w3v = w3n;
            }
            float mr = rv[0], ms = sv[0];
#pragma unroll
            for (int j = 1; j < 8; ++j) { mr = fmaxf(mr, rv[j]); ms = fmaxf(ms, sv[j]); }
            mx0 = fmaxf(mx0, mr + b3a);   // relu folded via mx >= 0 init
            mx1 = fmaxf(mx1, ms + b3b);
        }

        // final BN affine (a3 > 0 => commutes with max)
        out[p * 128 + c]      = fmaf(a3a, mx0, c3a);
        out[p * 128 + 64 + c] = fmaf(a3b, mx1, c3b);
    }
}

extern "C" void kernel_launch(void* const* d_in, const int* in_sizes, int n_in,
                              void* d_out, int out_size, void* d_ws, size_t ws_size,
                              hipStream_t stream) {
    const float* pos = (const float*)d_in[1];
    const float* W1 = (const float*)d_in[3];
    const float* b1 = (const float*)d_in[4];
    const float* g1 = (const float*)d_in[5];
    const float* be1 = (const float*)d_in[6];
    const float* m1 = (const float*)d_in[7];
    const float* v1 = (const float*)d_in[8];
    const float* W2 = (const float*)d_in[9];
    const float* b2 = (const float*)d_in[10];
    const float* g2 = (const float*)d_in[11];
    const float* be2 = (const float*)d_in[12];
    const float* m2 = (const float*)d_in[13];
    const float* v2 = (const float*)d_in[14];
    const float* W3 = (const float*)d_in[15];
    const float* b3 = (const float*)d_in[16];
    const float* g3 = (const float*)d_in[17];
    const float* be3 = (const float*)d_in[18];
    const float* m3 = (const float*)d_in[19];
    const float* v3 = (const float*)d_in[20];

    // reset the work-queue counter (graph-capturable async memset)
    hipMemsetAsync(d_ws, 0, sizeof(int), stream);

    // 512 blocks x 4 waves; waves grab points dynamically
    sa_lds<<<512, 256, 0, stream>>>(pos,
                                    W1, b1, g1, be1, m1, v1,
                                    W2, b2, g2, be2, m2, v2,
                                    W3, b3, g3, be3, m3, v3,
                                    (float*)d_out, (int*)d_ws);
}

// Round 10
// 201.790 us; speedup vs baseline: 1.2107x; 1.2107x over previous
//
#include <hip/hip_runtime.h>
#include <stdint.h>

#define N_PTS 8192
#define SEG 1024

// d^2 exactly as numpy/jax f32: mul,mul,mul,(add),add — no FMA contraction.
__device__ __forceinline__ float sq3(float dx, float dy, float dz) {
#pragma clang fp contract(off)
    float xx = dx * dx;
    float yy = dy * dy;
    float zz = dz * dz;
    return (xx + yy) + zz;
}

// Cross-lane broadcast through the register file.
__device__ __forceinline__ float bcastf(float v, int k) {
    return __int_as_float(__builtin_amdgcn_readlane(__float_as_int(v), k));
}

__global__ __launch_bounds__(256, 2)
void sa_v2(const float* __restrict__ pos,
           const float* __restrict__ W1, const float* __restrict__ b1,
           const float* __restrict__ g1, const float* __restrict__ be1,
           const float* __restrict__ m1, const float* __restrict__ v1,
           const float* __restrict__ W2, const float* __restrict__ b2,
           const float* __restrict__ g2, const float* __restrict__ be2,
           const float* __restrict__ m2, const float* __restrict__ v2,
           const float* __restrict__ W3, const float* __restrict__ b3,
           const float* __restrict__ g3, const float* __restrict__ be3,
           const float* __restrict__ m3, const float* __restrict__ v3,
           float* __restrict__ out, int* __restrict__ ctr)
{
    __shared__ float a1s[64], c1s[64], a2s[64], c2s[64];
    __shared__ float w3b_lds[64 * 64];   // [k][c] = a2[k]*W3[k][64+c]  (16 KB)
    __shared__ int nbrs[4][64];

    const int tid  = threadIdx.x;
    const int lane = tid & 63;
    const int w    = tid >> 6;
    const int c    = lane;

    // ---------- BN affine coefficients ----------
    if (tid < 64) {
        float a1 = g1[tid] / sqrtf(v1[tid] + 1e-5f);
        a1s[tid] = a1;
        c1s[tid] = be1[tid] - m1[tid] * a1;
        float a2 = g2[tid] / sqrtf(v2[tid] + 1e-5f);
        a2s[tid] = a2;
        c2s[tid] = be2[tid] - m2[tid] * a2;
    }
    __syncthreads();

    // ---------- stage w3b into LDS: [k][c], bank-conflict-free reads ----------
    for (int idx = tid; idx < 4096; idx += 256) {
        int cc = idx & 63, k = idx >> 6;
        w3b_lds[k * 64 + cc] = a2s[k] * W3[k * 128 + 64 + cc];
    }

    // ---------- per-lane folded weights (lane = channel c) ----------
    const float w1x = W1[c], w1y = W1[64 + c], w1z = W1[128 + c];
    const float b1v = b1[c];

    float w2c[64];                       // resident (64 VGPR)
    float b2c = b2[c];
#pragma unroll
    for (int k = 0; k < 64; ++k) {
        float wv = W2[k * 64 + c];
        w2c[k] = a1s[k] * wv;
        b2c = fmaf(c1s[k], wv, b2c);
    }

    float w3a[64];                       // resident (64 VGPR)
    float b3a = b3[c], b3b = b3[64 + c];
#pragma unroll
    for (int k = 0; k < 64; ++k) {
        float wa = W3[k * 128 + c];
        w3a[k] = a2s[k] * wa;
        b3a = fmaf(c2s[k], wa, b3a);
        b3b = fmaf(c2s[k], W3[k * 128 + 64 + c], b3b);
    }

    const float a3a = g3[c] / sqrtf(v3[c] + 1e-5f);
    const float c3a = be3[c] - m3[c] * a3a;
    const float a3b = g3[64 + c] / sqrtf(v3[64 + c] + 1e-5f);
    const float c3b = be3[64 + c] - m3[64 + c] * a3b;

    __syncthreads();   // w3b_lds staged; below is wave-local

    const float R2 = (float)(0.2 * 0.2);   // f32(0.04), one ulp below 0.2f*0.2f
    const unsigned R2bits = __float_as_uint(R2);
    const unsigned long long below = (1ULL << lane) - 1ULL;

    // ---------- dynamic per-point work queue ----------
    for (;;) {
        int p0 = 0;
        if (lane == 0) p0 = atomicAdd(ctr, 1);
        const int p = __builtin_amdgcn_readfirstlane(p0);
        if (p >= N_PTS) break;

        const int base = p & ~(SEG - 1);
        const float px = pos[p * 3 + 0], py = pos[p * 3 + 1], pz = pos[p * 3 + 2];

        // ---- ball query: 1024 candidates, 16 per lane (proven exact) ----
        unsigned bits[16];
        int cnt = 0;
#pragma unroll
        for (int s = 0; s < 16; ++s) {
            int j = base + s * 64 + lane;
            float dx = pos[j * 3 + 0] - px;
            float dy = pos[j * 3 + 1] - py;
            float dz = pos[j * 3 + 2] - pz;
            float d2 = sq3(dx, dy, dz);
            bool ok = (d2 <= R2);
            bits[s] = ok ? __float_as_uint(d2) : 0xFFFFFFFFu;
            cnt += __popcll(__ballot(ok));
        }

        unsigned selm = 0;
        if (cnt <= 64) {
#pragma unroll
            for (int s = 0; s < 16; ++s)
                selm |= (bits[s] != 0xFFFFFFFFu ? 1u : 0u) << s;
        } else {
            // exact 64-smallest selection, index tie-break (matches lax.top_k)
            unsigned lo = 0, hi = R2bits;
            while (lo < hi) {
                unsigned mid = lo + ((hi - lo) >> 1);
                int cc = 0;
#pragma unroll
                for (int s = 0; s < 16; ++s)
                    cc += __popcll(__ballot(bits[s] <= mid));
                if (cc >= 64) hi = mid; else lo = mid + 1;
            }
            const unsigned T = lo;
            int c1n = 0;
#pragma unroll
            for (int s = 0; s < 16; ++s)
                c1n += __popcll(__ballot(bits[s] < T));
            const int need = 64 - c1n;
            int eqbase = 0;
#pragma unroll
            for (int s = 0; s < 16; ++s) {
                unsigned long long em = __ballot(bits[s] == T);
                int rank = eqbase + __popcll(em & below);
                bool sel = (bits[s] < T) | ((bits[s] == T) & (rank < need));
                selm |= (sel ? 1u : 0u) << s;
                eqbase += __popcll(em);
            }
        }

        // ---- compact selected neighbor indices into LDS (once per point) ----
        int nsel = 0;
#pragma unroll
        for (int s = 0; s < 16; ++s) {
            bool sel = (selm >> s) & 1u;
            unsigned long long m = __ballot(sel);
            int mypos = nsel + __popcll(m & below);
            if (sel) nbrs[w][mypos] = base + s * 64 + lane;
            nsel += __popcll(m);
        }
        asm volatile("s_waitcnt lgkmcnt(0)" ::: "memory");

        // lane e holds edge e's relative position (nsel <= 64 always)
        const int myj = (lane < nsel) ? nbrs[w][lane] : p;
        const float relx = pos[myj * 3 + 0] - px;
        const float rely = pos[myj * 3 + 1] - py;
        const float relz = pos[myj * 3 + 2] - pz;

        // ---- MLP + max: 4-edge batches; w2c/w3a from regs, w3b streamed LDS ----
        float mx0 = 0.f, mx1 = 0.f;   // relu folded: maxes start at 0
        const int nb = (nsel + 3) >> 2;
        for (int bb = 0; bb < nb; ++bb) {
            const int eb = bb * 4;

            // L1: lane's channel for 4 edges (dup-pad tail; max-safe)
            float h1v[4];
#pragma unroll
            for (int j = 0; j < 4; ++j) {
                int ej = eb + j;  ej = (ej < nsel) ? ej : (nsel - 1);
                float rx = bcastf(relx, ej);
                float ry = bcastf(rely, ej);
                float rz = bcastf(relz, ej);
                h1v[j] = fmaxf(fmaf(rx, w1x, fmaf(ry, w1y, fmaf(rz, w1z, b1v))), 0.f);
            }

            // L2: z2[c][j] = b2c + sum_k h1[k][j] * w2c[k]   (fully unrolled)
            float z2v[4] = {b2c, b2c, b2c, b2c};
#pragma unroll
            for (int k = 0; k < 64; ++k) {
#pragma unroll
                for (int j = 0; j < 4; ++j)
                    z2v[j] = fmaf(bcastf(h1v[j], k), w2c[k], z2v[j]);
            }
            float h2v[4];
#pragma unroll
            for (int j = 0; j < 4; ++j) h2v[j] = fmaxf(z2v[j], 0.f);

            // L3: rv = h2 . w3a (regs), sv = h2 . w3b (LDS stream, 1 read / k)
            float rv[4] = {0.f, 0.f, 0.f, 0.f};
            float sv[4] = {0.f, 0.f, 0.f, 0.f};
#pragma unroll
            for (int k = 0; k < 64; ++k) {
                const float wbk = w3b_lds[k * 64 + c];   // ds_read_b32, 2-way = free
#pragma unroll
                for (int j = 0; j < 4; ++j) {
                    const float u = bcastf(h2v[j], k);
                    rv[j] = fmaf(u, w3a[k], rv[j]);
                    sv[j] = fmaf(u, wbk,   sv[j]);
                }
            }
            float mr = fmaxf(fmaxf(rv[0], rv[1]), fmaxf(rv[2], rv[3]));
            float ms = fmaxf(fmaxf(sv[0], sv[1]), fmaxf(sv[2], sv[3]));
            mx0 = fmaxf(mx0, mr + b3a);
            mx1 = fmaxf(mx1, ms + b3b);
        }

        // final BN affine (a3 > 0 => commutes with max)
        out[p * 128 + c]      = fmaf(a3a, mx0, c3a);
        out[p * 128 + 64 + c] = fmaf(a3b, mx1, c3b);
    }
}

extern "C" void kernel_launch(void* const* d_in, const int* in_sizes, int n_in,
                              void* d_out, int out_size, void* d_ws, size_t ws_size,
                              hipStream_t stream) {
    const float* pos = (const float*)d_in[1];
    const float* W1 = (const float*)d_in[3];
    const float* b1 = (const float*)d_in[4];
    const float* g1 = (const float*)d_in[5];
    const float* be1 = (const float*)d_in[6];
    const float* m1 = (const float*)d_in[7];
    const float* v1 = (const float*)d_in[8];
    const float* W2 = (const float*)d_in[9];
    const float* b2 = (const float*)d_in[10];
    const float* g2 = (const float*)d_in[11];
    const float* be2 = (const float*)d_in[12];
    const float* m2 = (const float*)d_in[13];
    const float* v2 = (const float*)d_in[14];
    const float* W3 = (const float*)d_in[15];
    const float* b3 = (const float*)d_in[16];
    const float* g3 = (const float*)d_in[17];
    const float* be3 = (const float*)d_in[18];
    const float* m3 = (const float*)d_in[19];
    const float* v3 = (const float*)d_in[20];

    // reset the work-queue counter (graph-capturable async memset)
    hipMemsetAsync(d_ws, 0, sizeof(int), stream);

    // 512 blocks x 4 waves; waves grab points dynamically
    sa_v2<<<512, 256, 0, stream>>>(pos,
                                   W1, b1, g1, be1, m1, v1,
                                   W2, b2, g2, be2, m2, v2,
                                   W3, b3, g3, be3, m3, v3,
                                   (float*)d_out, (int*)d_ws);
}